// Round 2
// baseline (49.210 us; speedup 1.0000x reference)
//
#include <hip/hip_runtime.h>

#define B_TOTAL 4194304
#define NPAIR   (B_TOTAL / 2)
#define NTHR    256

__device__ __forceinline__ float fast_tanh(float x) {
    float ax = fabsf(x);
    float e  = __expf(-2.0f * ax);
    float t  = (1.0f - e) / (1.0f + e);
    return copysignf(t, x);
}

__device__ __forceinline__ void norm_sc(float s, float c, float& S, float& C) {
    float r2 = fmaf(s, s, c * c);
    if (r2 > 1e-20f) {
        float iv = rsqrtf(r2);
        S = s * iv; C = c * iv;
    } else {
        S = 0.0f; C = 1.0f;
    }
}

// per-sample math: 6 tanh'd preds, 6 targets, 3 P5 targets -> 3 partial sums
__device__ __forceinline__ void sample_loss(
    float s1, float c1, float s2, float c2, float s3, float c3,
    float t0, float t1, float t2, float t3, float t4, float t5,
    float q0, float q1, float q2,
    float& acc_sc, float& acc_circ, float& acc_wc)
{
    const float d1 = 671.83f, a2 = 431.8f, d2 = 139.7f, a3 = -20.32f, D4 = 431.8f;
    const float inv_r = 1.0f / 900.0f;

    float d;
    d = s1 - t0; acc_sc += d * d;
    d = c1 - t1; acc_sc += d * d;
    d = s2 - t2; acc_sc += d * d;
    d = c2 - t3; acc_sc += d * d;
    d = s3 - t4; acc_sc += d * d;
    d = c3 - t5; acc_sc += d * d;

    float r21 = fmaf(s1, s1, c1 * c1);
    float r22 = fmaf(s2, s2, c2 * c2);
    float r23 = fmaf(s3, s3, c3 * c3);
    d = r21 - 1.0f; acc_circ += d * d;
    d = r22 - 1.0f; acc_circ += d * d;
    d = r23 - 1.0f; acc_circ += d * d;

    float S1, C1, S2, C2, S3, C3;
    norm_sc(s1, c1, S1, C1);
    norm_sc(s2, c2, S2, C2);
    norm_sc(s3, c3, S3, C3);

    float s23 = fmaf(S2, C3, C2 * S3);
    float c23 = fmaf(C2, C3, -S2 * S3);
    float pxp = fmaf(a3, c23, a2 * C2) + D4 * s23;
    float x = fmaf(C1, pxp, -S1 * d2);
    float y = fmaf(S1, pxp,  C1 * d2);
    float z = d1 - fmaf(a3, s23, a2 * S2) + D4 * c23;

    float dx = (x - q0) * inv_r;
    float dy = (y - q1) * inv_r;
    float dz = (z - q2) * inv_r;
    acc_wc += fmaf(dx, dx, fmaf(dy, dy, dz * dz));
}

__global__ __launch_bounds__(NTHR) void ik_loss_partial(
    const float* __restrict__ pred_raw,
    const float* __restrict__ target_sc,
    const float* __restrict__ p5t,
    double* __restrict__ partial,
    int nblk)
{
    float acc_sc = 0.f, acc_wc = 0.f, acc_circ = 0.f;

    const int stride = nblk * NTHR;
    for (int j = blockIdx.x * NTHR + threadIdx.x; j < NPAIR; j += stride) {
        // pair j covers samples 2j, 2j+1: 12 contiguous floats (48B, 16B-aligned)
        const float4* pr = (const float4*)(pred_raw  + 12 * (size_t)j);
        const float4* tg = (const float4*)(target_sc + 12 * (size_t)j);
        const float2* qv = (const float2*)(p5t       +  6 * (size_t)j);
        float4 pA = pr[0], pB = pr[1], pC = pr[2];
        float4 tA = tg[0], tB = tg[1], tC = tg[2];
        float2 qA = qv[0], qB = qv[1], qC = qv[2];

        // sample 0 of the pair
        {
            float s1 = fast_tanh(pA.x), c1 = fast_tanh(pA.y);
            float s2 = fast_tanh(pA.z), c2 = fast_tanh(pA.w);
            float s3 = fast_tanh(pB.x), c3 = fast_tanh(pB.y);
            sample_loss(s1, c1, s2, c2, s3, c3,
                        tA.x, tA.y, tA.z, tA.w, tB.x, tB.y,
                        qA.x, qA.y, qB.x,
                        acc_sc, acc_circ, acc_wc);
        }
        // sample 1 of the pair
        {
            float s1 = fast_tanh(pB.z), c1 = fast_tanh(pB.w);
            float s2 = fast_tanh(pC.x), c2 = fast_tanh(pC.y);
            float s3 = fast_tanh(pC.z), c3 = fast_tanh(pC.w);
            sample_loss(s1, c1, s2, c2, s3, c3,
                        tB.z, tB.w, tC.x, tC.y, tC.z, tC.w,
                        qB.y, qC.x, qC.y,
                        acc_sc, acc_circ, acc_wc);
        }
    }

    const double k_sc = 1.0  / (6.0 * (double)B_TOTAL);
    const double k_wc = 2.0  / (3.0 * (double)B_TOTAL);
    const double k_ci = 0.05 / (3.0 * (double)B_TOTAL);
    double v = (double)acc_sc * k_sc + (double)acc_wc * k_wc + (double)acc_circ * k_ci;

    #pragma unroll
    for (int off = 32; off > 0; off >>= 1) v += __shfl_down(v, off, 64);

    __shared__ double sm[NTHR / 64];
    int lane = threadIdx.x & 63, w = threadIdx.x >> 6;
    if (lane == 0) sm[w] = v;
    __syncthreads();
    if (threadIdx.x == 0) {
        double t = 0.0;
        #pragma unroll
        for (int jj = 0; jj < NTHR / 64; ++jj) t += sm[jj];
        partial[blockIdx.x] = t;
    }
}

__global__ __launch_bounds__(NTHR) void ik_loss_final(
    const double* __restrict__ partial, float* __restrict__ out, int nblk)
{
    double v = 0.0;
    for (int i = threadIdx.x; i < nblk; i += NTHR) v += partial[i];
    #pragma unroll
    for (int off = 32; off > 0; off >>= 1) v += __shfl_down(v, off, 64);

    __shared__ double sm[NTHR / 64];
    int lane = threadIdx.x & 63, w = threadIdx.x >> 6;
    if (lane == 0) sm[w] = v;
    __syncthreads();
    if (threadIdx.x == 0) {
        double t = 0.0;
        #pragma unroll
        for (int jj = 0; jj < NTHR / 64; ++jj) t += sm[jj];
        out[0] = (float)t;
    }
}

extern "C" void kernel_launch(void* const* d_in, const int* in_sizes, int n_in,
                              void* d_out, int out_size, void* d_ws, size_t ws_size,
                              hipStream_t stream) {
    const float* pred_raw  = (const float*)d_in[0];
    const float* target_sc = (const float*)d_in[1];
    const float* p5_target = (const float*)d_in[2];
    double* partial = (double*)d_ws;
    float*  out     = (float*)d_out;

    // 2048 blocks = 8 blocks/CU (32 waves/CU); fall back if ws is small
    int nblk = (ws_size >= 2048 * sizeof(double)) ? 2048 : 1024;

    ik_loss_partial<<<nblk, NTHR, 0, stream>>>(pred_raw, target_sc, p5_target, partial, nblk);
    ik_loss_final<<<1, NTHR, 0, stream>>>(partial, out, nblk);
}

// Round 3
// 43.157 us; speedup vs baseline: 1.1403x; 1.1403x over previous
//
#include <hip/hip_runtime.h>

#define B_TOTAL 4194304
#define NBLK 1024
#define NTHR 256
#define TSTRIDE (NBLK * NTHR)   // 262144; B_TOTAL = 16 * TSTRIDE exactly

__device__ __forceinline__ float fast_tanh(float x) {
    float ax = fabsf(x);
    float e  = __expf(-2.0f * ax);
    float t  = (1.0f - e) / (1.0f + e);
    return copysignf(t, x);
}

__device__ __forceinline__ void norm_sc(float s, float c, float& S, float& C) {
    float r2 = fmaf(s, s, c * c);
    if (r2 > 1e-20f) {
        float iv = rsqrtf(r2);
        S = s * iv; C = c * iv;
    } else {
        S = 0.0f; C = 1.0f;
    }
}

__device__ __forceinline__ void sample_loss(
    float2 p01, float2 p23, float2 p45,
    float2 t01, float2 t23, float2 t45,
    float q0, float q1, float q2,
    float& acc_sc, float& acc_circ, float& acc_wc)
{
    const float d1 = 671.83f, a2 = 431.8f, d2 = 139.7f, a3 = -20.32f, D4 = 431.8f;
    const float inv_r = 1.0f / 900.0f;

    float s1 = fast_tanh(p01.x), c1 = fast_tanh(p01.y);
    float s2 = fast_tanh(p23.x), c2 = fast_tanh(p23.y);
    float s3 = fast_tanh(p45.x), c3 = fast_tanh(p45.y);

    float d;
    d = s1 - t01.x; acc_sc += d * d;
    d = c1 - t01.y; acc_sc += d * d;
    d = s2 - t23.x; acc_sc += d * d;
    d = c2 - t23.y; acc_sc += d * d;
    d = s3 - t45.x; acc_sc += d * d;
    d = c3 - t45.y; acc_sc += d * d;

    float r21 = fmaf(s1, s1, c1 * c1);
    float r22 = fmaf(s2, s2, c2 * c2);
    float r23 = fmaf(s3, s3, c3 * c3);
    d = r21 - 1.0f; acc_circ += d * d;
    d = r22 - 1.0f; acc_circ += d * d;
    d = r23 - 1.0f; acc_circ += d * d;

    float S1, C1, S2, C2, S3, C3;
    norm_sc(s1, c1, S1, C1);
    norm_sc(s2, c2, S2, C2);
    norm_sc(s3, c3, S3, C3);

    float s23 = fmaf(S2, C3, C2 * S3);
    float c23 = fmaf(C2, C3, -S2 * S3);
    float pxp = fmaf(a3, c23, a2 * C2) + D4 * s23;
    float x = fmaf(C1, pxp, -S1 * d2);
    float y = fmaf(S1, pxp,  C1 * d2);
    float z = d1 - fmaf(a3, s23, a2 * S2) + D4 * c23;

    float dx = (x - q0) * inv_r;
    float dy = (y - q1) * inv_r;
    float dz = (z - q2) * inv_r;
    acc_wc += fmaf(dx, dx, fmaf(dy, dy, dz * dz));
}

__global__ __launch_bounds__(NTHR) void ik_loss_partial(
    const float* __restrict__ pred_raw,
    const float* __restrict__ target_sc,
    const float* __restrict__ p5t,
    double* __restrict__ partial)
{
    float acc_sc = 0.f, acc_wc = 0.f, acc_circ = 0.f;

    // two interleaved sample streams per iteration -> ~14 loads in flight
    for (int i = blockIdx.x * NTHR + threadIdx.x; i < B_TOTAL; i += 2 * TSTRIDE) {
        const int ia = i;
        const int ib = i + TSTRIDE;   // always < B_TOTAL (16 strides total)

        const float2* prA = (const float2*)(pred_raw  + 6 * (size_t)ia);
        const float2* tgA = (const float2*)(target_sc + 6 * (size_t)ia);
        const float*  qA  = p5t + 3 * (size_t)ia;
        const float2* prB = (const float2*)(pred_raw  + 6 * (size_t)ib);
        const float2* tgB = (const float2*)(target_sc + 6 * (size_t)ib);
        const float*  qB  = p5t + 3 * (size_t)ib;

        // issue all loads for both samples before any dependent math
        float2 pA0 = prA[0], pA1 = prA[1], pA2 = prA[2];
        float2 tA0 = tgA[0], tA1 = tgA[1], tA2 = tgA[2];
        float  qA0 = qA[0],  qA1 = qA[1],  qA2 = qA[2];
        float2 pB0 = prB[0], pB1 = prB[1], pB2 = prB[2];
        float2 tB0 = tgB[0], tB1 = tgB[1], tB2 = tgB[2];
        float  qB0 = qB[0],  qB1 = qB[1],  qB2 = qB[2];

        sample_loss(pA0, pA1, pA2, tA0, tA1, tA2, qA0, qA1, qA2,
                    acc_sc, acc_circ, acc_wc);
        sample_loss(pB0, pB1, pB2, tB0, tB1, tB2, qB0, qB1, qB2,
                    acc_sc, acc_circ, acc_wc);
    }

    const double k_sc = 1.0  / (6.0 * (double)B_TOTAL);
    const double k_wc = 2.0  / (3.0 * (double)B_TOTAL);
    const double k_ci = 0.05 / (3.0 * (double)B_TOTAL);
    double v = (double)acc_sc * k_sc + (double)acc_wc * k_wc + (double)acc_circ * k_ci;

    #pragma unroll
    for (int off = 32; off > 0; off >>= 1) v += __shfl_down(v, off, 64);

    __shared__ double sm[NTHR / 64];
    int lane = threadIdx.x & 63, w = threadIdx.x >> 6;
    if (lane == 0) sm[w] = v;
    __syncthreads();
    if (threadIdx.x == 0) {
        double t = 0.0;
        #pragma unroll
        for (int jj = 0; jj < NTHR / 64; ++jj) t += sm[jj];
        partial[blockIdx.x] = t;
    }
}

__global__ __launch_bounds__(NTHR) void ik_loss_final(
    const double* __restrict__ partial, float* __restrict__ out)
{
    double v = 0.0;
    for (int i = threadIdx.x; i < NBLK; i += NTHR) v += partial[i];
    #pragma unroll
    for (int off = 32; off > 0; off >>= 1) v += __shfl_down(v, off, 64);

    __shared__ double sm[NTHR / 64];
    int lane = threadIdx.x & 63, w = threadIdx.x >> 6;
    if (lane == 0) sm[w] = v;
    __syncthreads();
    if (threadIdx.x == 0) {
        double t = 0.0;
        #pragma unroll
        for (int jj = 0; jj < NTHR / 64; ++jj) t += sm[jj];
        out[0] = (float)t;
    }
}

extern "C" void kernel_launch(void* const* d_in, const int* in_sizes, int n_in,
                              void* d_out, int out_size, void* d_ws, size_t ws_size,
                              hipStream_t stream) {
    const float* pred_raw  = (const float*)d_in[0];
    const float* target_sc = (const float*)d_in[1];
    const float* p5_target = (const float*)d_in[2];
    double* partial = (double*)d_ws;
    float*  out     = (float*)d_out;

    ik_loss_partial<<<NBLK, NTHR, 0, stream>>>(pred_raw, target_sc, p5_target, partial);
    ik_loss_final<<<1, NTHR, 0, stream>>>(partial, out);
}